// Round 13
// baseline (404.553 us; speedup 1.0000x reference)
//
#include <hip/hip_runtime.h>
#include <stdint.h>

typedef __attribute__((ext_vector_type(8))) short bf16x8;
typedef __attribute__((ext_vector_type(4))) float f32x4;
typedef __attribute__((ext_vector_type(4))) float fl4;
typedef __attribute__((ext_vector_type(4))) unsigned short u16x4;
typedef __attribute__((ext_vector_type(8))) unsigned short u16x8;

constexpr int SEQ = 2048;
constexpr int DMODEL = 1024;
constexpr int NH = 16;
constexpr int DKH = 64;
constexpr float SEXP = 0.18033688f;  // log2(e)/8 — exp(s/8) == exp2(s*SEXP)

__device__ __forceinline__ unsigned short f2bf(float x) {
  union { float f; uint32_t u; } c;
  c.f = x;
  uint32_t u = c.u;
  u += 0x7FFFu + ((u >> 16) & 1u);
  return (unsigned short)(u >> 16);
}

__device__ __forceinline__ float bf2f(unsigned short u) {
  union { uint32_t u; float f; } c;
  c.u = ((uint32_t)u) << 16;
  return c.f;
}

__device__ __forceinline__ uint32_t cvtpk(float lo, float hi) {
  uint32_t r;
  asm("v_cvt_pk_bf16_f32 %0, %1, %2" : "=v"(r) : "v"(lo), "v"(hi));
  return r;
}

#if __has_builtin(__builtin_amdgcn_exp2f)
__device__ __forceinline__ float fexp2(float x) { return __builtin_amdgcn_exp2f(x); }
#else
__device__ __forceinline__ float fexp2(float x) { return exp2f(x); }
#endif

__device__ __forceinline__ int swz(int row) { return (row & 3) ^ ((row >> 2) & 3); }

__device__ __forceinline__ void gload16(const unsigned short* g, unsigned short* l) {
  __builtin_amdgcn_global_load_lds((const __attribute__((address_space(1))) void*)g,
                                   (__attribute__((address_space(3))) void*)l, 16, 0, 0);
}

// ---------------- fp32 -> bf16 conversions (weights only) ----------------
__global__ __launch_bounds__(256) void cvtk(
    const float* __restrict__ s0, const float* __restrict__ s1, const float* __restrict__ s2,
    unsigned short* __restrict__ d0, unsigned short* __restrict__ d1, unsigned short* __restrict__ d2) {
  const float* s = blockIdx.y == 0 ? s0 : blockIdx.y == 1 ? s1 : s2;
  unsigned short* d = blockIdx.y == 0 ? d0 : blockIdx.y == 1 ? d1 : d2;
  const size_t i = ((size_t)blockIdx.x * 256 + threadIdx.x) * 8;
  fl4 a = *(const fl4*)(s + i);
  fl4 c = *(const fl4*)(s + i + 4);
  u16x8 r;
#pragma unroll
  for (int j = 0; j < 4; ++j) { r[j] = f2bf(a[j]); r[4 + j] = f2bf(c[j]); }
  *(u16x8*)(d + i) = r;
}

__global__ __launch_bounds__(256) void cvt1(
    const float* __restrict__ s, unsigned short* __restrict__ d) {
  const size_t i = ((size_t)blockIdx.x * 256 + threadIdx.x) * 8;
  fl4 a = *(const fl4*)(s + i);
  fl4 c = *(const fl4*)(s + i + 4);
  u16x8 r;
#pragma unroll
  for (int j = 0; j < 4; ++j) { r[j] = f2bf(a[j]); r[4 + j] = f2bf(c[j]); }
  *(u16x8*)(d + i) = r;
}

// ---------------- Fused QKV projection: one launch, 1536 blocks (unchanged, proven) ----------------
__global__ __launch_bounds__(256, 2) void gemmqkv(
    const float* __restrict__ Xq, const float* __restrict__ Xk, const float* __restrict__ Xv,
    const unsigned short* __restrict__ Wb,   // [3][1024][1024] bf16, Wq|Wk|Wv
    const float* __restrict__ bq, const float* __restrict__ bk, const float* __restrict__ bv,
    unsigned short* __restrict__ Qp, unsigned short* __restrict__ Kp, unsigned short* __restrict__ Vt) {
  constexpr int K = DMODEL;
  __shared__ unsigned short As[2][128 * 32];
  __shared__ unsigned short Bs[2][128 * 32];
  const int tid = threadIdx.x;
  const int wave = tid >> 6, lane = tid & 63;
  const int g = lane >> 4, ln = lane & 15;
  const int o = blockIdx.x;                 // 1536 blocks
  const int x = o & 7, j = o >> 3;          // XCD x, j in [0,192)
  const int si = j >> 5, w = j & 31;        // 6 supertiles of 32 blocks per XCD
  const int seg = si >> 1;                  // 2 supertiles per segment per XCD
  const int r0 = (x * 8 + (si & 1) * 4 + (w & 3)) * 128;
  const int c0 = (w >> 2) * 128;
  const int wr = (wave >> 1) * 64, wc = (wave & 1) * 64;
  const int arow = tid >> 2, cc = tid & 3;

  const float* A = seg == 0 ? Xq : seg == 1 ? Xk : Xv;
  const unsigned short* Bw = Wb + (size_t)seg * DMODEL * DMODEL;
  const float* bias = seg == 0 ? bq : seg == 1 ? bk : bv;
  const float ascale = seg == 0 ? SEXP : 1.0f;

  f32x4 acc[4][4] = {};
  fl4 ar[2][2];

  auto LOADA = [&](int kt) {
#pragma unroll
    for (int i = 0; i < 2; ++i) {
      const size_t ao = (size_t)(r0 + arow + i * 64) * K + kt + cc * 8;
      ar[i][0] = *(const fl4*)(A + ao);
      ar[i][1] = *(const fl4*)(A + ao + 4);
    }
  };
  auto WRITEA = [&](int buf) {
#pragma unroll
    for (int i = 0; i < 2; ++i) {
      const int row = arow + i * 64;
      const int ch = (cc ^ swz(row)) * 8;
      union { uint32_t u[4]; u16x8 v; } pk;
      pk.u[0] = cvtpk(ar[i][0][0], ar[i][0][1]);
      pk.u[1] = cvtpk(ar[i][0][2], ar[i][0][3]);
      pk.u[2] = cvtpk(ar[i][1][0], ar[i][1][1]);
      pk.u[3] = cvtpk(ar[i][1][2], ar[i][1][3]);
      *(u16x8*)(As[buf] + row * 32 + ch) = pk.v;
    }
  };
  auto STAGEB = [&](int buf, int kt) {
#pragma unroll
    for (int i = 0; i < 2; ++i) {
      const int row = i * 64 + (tid >> 2);
      const int cs = ((tid & 3) ^ swz(row)) * 8;
      gload16(Bw + (size_t)(c0 + row) * K + kt + cs, Bs[buf] + (i * 256 + wave * 64) * 8);
    }
  };

  LOADA(0);
  WRITEA(0);
  STAGEB(0, 0);
  __syncthreads();

  for (int t = 0; t < K / 32; ++t) {
    const int buf = t & 1;
    if (t + 1 < K / 32) { LOADA((t + 1) * 32); STAGEB(buf ^ 1, (t + 1) * 32); }
    bf16x8 af[4], bfr[4];
#pragma unroll
    for (int m = 0; m < 4; ++m) {
      const int row = wr + m * 16 + ln;
      af[m] = *(const bf16x8*)(As[buf] + row * 32 + ((g ^ swz(row)) * 8));
    }
#pragma unroll
    for (int n = 0; n < 4; ++n) {
      const int row = wc + n * 16 + ln;
      bfr[n] = *(const bf16x8*)(Bs[buf] + row * 32 + ((g ^ swz(row)) * 8));
    }
#pragma unroll
    for (int m = 0; m < 4; ++m)
#pragma unroll
      for (int n = 0; n < 4; ++n)
        acc[m][n] = __builtin_amdgcn_mfma_f32_16x16x32_bf16(af[m], bfr[n], acc[m][n], 0, 0, 0);
    if (t + 1 < K / 32) WRITEA(buf ^ 1);  // buf^1 not read by anyone during iter t
    __syncthreads();
  }

  // epilogue: C/D layout col = lane&15, row = (lane>>4)*4 + reg
#pragma unroll
  for (int m = 0; m < 4; ++m) {
    const int row = r0 + wr + m * 16 + g * 4;
#pragma unroll
    for (int n = 0; n < 4; ++n) {
      const int col = c0 + wc + n * 16 + ln;
      const float bvv = bias[col];
      f32x4 v = acc[m][n];
      if (seg < 2) {
        unsigned short* C = seg == 0 ? Qp : Kp;
#pragma unroll
        for (int r = 0; r < 4; ++r) C[(size_t)(row + r) * DMODEL + col] = f2bf((v[r] + bvv) * ascale);
      } else {
        // V^T [b][h][d][s'], s' kv-permuted in each aligned 32-block:
        // s = 32*blk + 4*gp + rr + 16*mp -> s' = 32*blk + 8*gp + 4*mp + rr
        const int bb = row >> 11, sl = row & 2047;
        const int h = col >> 6, d = col & 63;
        const int sp = (sl & ~31) | (((sl >> 2) & 3) << 3) | (((sl >> 4) & 1) << 2);
        u16x4 pk;
#pragma unroll
        for (int r = 0; r < 4; ++r) pk[r] = f2bf(v[r] + bvv);
        *(u16x4*)(Vt + ((size_t)((bb * NH + h) * DKH + d)) * SEQ + sp) = pk;
      }
    }
  }
}

// ---------------- Output GEMM (unchanged, proven) ----------------
__global__ __launch_bounds__(256, 2) void gemmout(
    const unsigned short* __restrict__ A, const unsigned short* __restrict__ Bb,
    const float* __restrict__ bias, float* __restrict__ Cp) {
  constexpr int K = DMODEL;
  constexpr int N = DMODEL;
  __shared__ unsigned short As[2][128 * 32];
  __shared__ unsigned short Bs[2][128 * 32];
  const int tid = threadIdx.x;
  const int wave = tid >> 6, lane = tid & 63;
  const int g = lane >> 4, ln = lane & 15;
  const int o = blockIdx.x;                 // 512 blocks
  const int x = o & 7, idx = o >> 3;
  const int r0 = (x * 8 + (idx & 7)) * 128;
  const int c0 = (idx >> 3) * 128;
  const int wr = (wave >> 1) * 64, wc = (wave & 1) * 64;

  f32x4 acc[4][4] = {};

  auto STAGE = [&](int buf, int kt) {
#pragma unroll
    for (int i = 0; i < 2; ++i) {
      const int row = i * 64 + (tid >> 2);
      const int cs = ((tid & 3) ^ swz(row)) * 8;
      gload16(A + (size_t)(r0 + row) * K + kt + cs, As[buf] + (i * 256 + wave * 64) * 8);
      gload16(Bb + (size_t)(c0 + row) * K + kt + cs, Bs[buf] + (i * 256 + wave * 64) * 8);
    }
  };

  STAGE(0, 0);
  __syncthreads();

  for (int t = 0; t < K / 32; ++t) {
    const int buf = t & 1;
    if (t + 1 < K / 32) STAGE(buf ^ 1, (t + 1) * 32);
    bf16x8 af[4], bfr[4];
#pragma unroll
    for (int m = 0; m < 4; ++m) {
      const int row = wr + m * 16 + ln;
      af[m] = *(const bf16x8*)(As[buf] + row * 32 + ((g ^ swz(row)) * 8));
    }
#pragma unroll
    for (int n = 0; n < 4; ++n) {
      const int row = wc + n * 16 + ln;
      bfr[n] = *(const bf16x8*)(Bs[buf] + row * 32 + ((g ^ swz(row)) * 8));
    }
#pragma unroll
    for (int m = 0; m < 4; ++m)
#pragma unroll
      for (int n = 0; n < 4; ++n)
        acc[m][n] = __builtin_amdgcn_mfma_f32_16x16x32_bf16(af[m], bfr[n], acc[m][n], 0, 0, 0);
    __syncthreads();
  }

#pragma unroll
  for (int m = 0; m < 4; ++m) {
    const int row = r0 + wr + m * 16 + g * 4;
#pragma unroll
    for (int n = 0; n < 4; ++n) {
      const int col = c0 + wc + n * 16 + ln;
      const float bvv = bias[col];
      f32x4 v = acc[m][n];
#pragma unroll
      for (int r = 0; r < 4; ++r) Cp[(size_t)(row + r) * N + col] = v[r] + bvv;
    }
  }
}

// ---------------- Kernel A: head-softmax denominators (unchanged, proven) ----------------
__global__ __launch_bounds__(256, 3) void denomk(
    const unsigned short* __restrict__ Qp, const unsigned short* __restrict__ Kp,
    unsigned short* __restrict__ rDb) {
  __shared__ unsigned short Ks[2][128 * 64];
  const int tid = threadIdx.x, wave = tid >> 6, lane = tid & 63;
  const int g = lane >> 4, ln = lane & 15;
  const int o = blockIdx.x;
  const int l = (o & 7) * 256 + (o >> 3);
  const int b = l >> 9;
  const int qg = (l >> 4) & 31;
  const int kvg = l & 15;
  const int q0 = qg * 64, kvb = kvg * 128;
  const int kw = wave * 32;

  auto STAGE = [&](int buf, int h) {
#pragma unroll
    for (int i = 0; i < 4; ++i) {
      const int s = i * 256 + tid;
      const int row = s >> 3, c = s & 7;
      gload16(Kp + (size_t)(b * SEQ + kvb + row) * DMODEL + h * DKH + ((c ^ (row & 7)) * 8),
              Ks[buf] + (i * 256 + wave * 64) * 8);
    }
  };

  f32x4 psum[2][4] = {};

  STAGE(0, 0);
  __syncthreads();

  for (int h = 0; h < NH; ++h) {
    const int buf = h & 1;
    if (h + 1 < NH) STAGE(buf ^ 1, h + 1);
    bf16x8 qf[2][4];
#pragma unroll
    for (int ks = 0; ks < 2; ++ks)
#pragma unroll
      for (int n = 0; n < 4; ++n)
        qf[ks][n] = *(const bf16x8*)(Qp + (size_t)(b * SEQ + q0 + n * 16 + ln) * DMODEL + h * DKH + ks * 32 + g * 8);
    bf16x8 kf[2][2];
#pragma unroll
    for (int m = 0; m < 2; ++m)
#pragma unroll
      for (int ks = 0; ks < 2; ++ks) {
        const int r = kw + m * 16 + ln;
        const int cc = ks * 4 + g;
        kf[m][ks] = *(const bf16x8*)(Ks[buf] + r * 64 + ((cc ^ (r & 7)) * 8));
      }
    f32x4 s[2][4] = {};
#pragma unroll
    for (int m = 0; m < 2; ++m)
#pragma unroll
      for (int n = 0; n < 4; ++n) {
        s[m][n] = __builtin_amdgcn_mfma_f32_16x16x32_bf16(kf[m][0], qf[0][n], s[m][n], 0, 0, 0);
        s[m][n] = __builtin_amdgcn_mfma_f32_16x16x32_bf16(kf[m][1], qf[1][n], s[m][n], 0, 0, 0);
      }
#pragma unroll
    for (int m = 0; m < 2; ++m)
#pragma unroll
      for (int n = 0; n < 4; ++n)
#pragma unroll
        for (int r = 0; r < 4; ++r) psum[m][n][r] += fexp2(s[m][n][r]);  // Q pre-scaled by SEXP
    __syncthreads();
  }

#pragma unroll
  for (int m = 0; m < 2; ++m)
#pragma unroll
    for (int n = 0; n < 4; ++n) {
      u16x4 st;
#pragma unroll
      for (int r = 0; r < 4; ++r) st[r] = f2bf(1.0f / psum[m][n][r]);
      *(u16x4*)(rDb + (size_t)(b * SEQ + q0 + n * 16 + ln) * SEQ + kvb + kw + m * 16 + g * 4) = st;
    }
}

// ---------------- Kernel B: per-head flash PV — 2-wave q64 blocks, 2048 blocks = 8/CU ----------------
// Round-12 diagnosis: grid 1024 = 4 lockstep blocks/CU was the limiter (nothing saturated).
// Block: (b, head h, q64); 2 waves each own q32. kv32 steps, 16KB LDS -> up to 10 resident;
// grid provides 8/CU independent blocks to interleave stalls. Per-wave math byte-identical to
// round-12 (same fragments, MFMA order, zero-shuffle P via kv-permuted V, same rD indexing).
// __launch_bounds__(128,4) caps VGPR at 128 >> measured ~52 — no spill (round-9 lesson).
__global__ __launch_bounds__(128, 4) void flashk(
    const unsigned short* __restrict__ Qp, const unsigned short* __restrict__ Kp,
    const unsigned short* __restrict__ Vt, const unsigned short* __restrict__ rDb,
    unsigned short* __restrict__ Ab) {
  __shared__ unsigned short Ks[2][32 * 64];   // [kv32][dk64], chunk-swizzled (4KB each)
  __shared__ unsigned short Vs[2][64 * 32];   // [d64][kv32-permuted], chunk-swizzled (4KB each)
  const int tid = threadIdx.x, wave = tid >> 6, lane = tid & 63;
  const int g = lane >> 4, ln = lane & 15;
  const int o = blockIdx.x;                  // 2048 blocks
  const int l = (o & 7) * 256 + (o >> 3);    // XCD chunk: one b x 8 heads (K/V 4MB = one L2)
  const int b = l >> 9;
  const int h = (l >> 5) & 15;
  const int q0 = (l & 31) * 64 + wave * 32;

  bf16x8 qf[2][2];
#pragma unroll
  for (int ks = 0; ks < 2; ++ks)
#pragma unroll
    for (int n = 0; n < 2; ++n)
      qf[ks][n] = *(const bf16x8*)(Qp + (size_t)(b * SEQ + q0 + n * 16 + ln) * DMODEL + h * DKH + ks * 32 + g * 8);

  f32x4 ao[4][2] = {};
  const size_t rbase0 = (size_t)(b * SEQ + q0 + ln) * SEQ;
  const size_t kbase = (size_t)(b * SEQ) * DMODEL + h * DKH;
  const size_t vbase = (size_t)((b * NH + h) * DKH) * SEQ;

  auto STAGE = [&](int buf, int kv0) {  // 4 gloads per thread (K 4KB + V 4KB, 128 threads)
#pragma unroll
    for (int i = 0; i < 2; ++i) {
      const int idx = i * 128 + tid;
      {  // K tile: 32 rows x 128B (this head's dk64)
        const int row = idx >> 3, c = idx & 7;
        gload16(Kp + kbase + (size_t)(kv0 + row) * DMODEL + ((c ^ (row & 7)) * 8),
                Ks[buf] + (size_t)(i * 128 + wave * 64) * 8);
      }
      {  // V tile: 64 rows x 64B (global already kv-permuted)
        const int row = idx >> 2, c = idx & 3;
        gload16(Vt + vbase + (size_t)row * SEQ + kv0 + ((c ^ (row & 3)) * 8),
                Vs[buf] + (size_t)(i * 128 + wave * 64) * 8);
      }
    }
  };

  STAGE(0, 0);
  __syncthreads();

  for (int t = 0; t < SEQ / 32; ++t) {
    const int kv0 = t * 32, buf = t & 1;
    // rD prefetch (4 loads; latency hidden under the QK chain)
    u16x4 rdq[2][2];  // [n][m]
#pragma unroll
    for (int n = 0; n < 2; ++n)
#pragma unroll
      for (int m = 0; m < 2; ++m)
        rdq[n][m] = *(const u16x4*)(rDb + rbase0 + (size_t)(n * 16) * SEQ + kv0 + m * 16 + g * 4);
    if (t + 1 < SEQ / 32) STAGE(buf ^ 1, kv0 + 32);

    // QK^T: S^T[kv32, q32] (bit-identical MFMA sequence to denomk; Q pre-scaled by SEXP)
    f32x4 s2[2][2] = {};
    __builtin_amdgcn_s_setprio(1);
#pragma unroll
    for (int m = 0; m < 2; ++m) {
      const int row = m * 16 + ln;
#pragma unroll
      for (int ks = 0; ks < 2; ++ks) {
        const int cc = ks * 4 + g;
        bf16x8 kf = *(const bf16x8*)(Ks[buf] + row * 64 + ((cc ^ (row & 7)) * 8));
#pragma unroll
        for (int n = 0; n < 2; ++n)
          s2[m][n] = __builtin_amdgcn_mfma_f32_16x16x32_bf16(kf, qf[ks][n], s2[m][n], 0, 0, 0);
      }
    }
    __builtin_amdgcn_s_setprio(0);

    // P = exp2(S') * rD, packed in-register straight into the permuted B-frag:
    // elem j of lane-group g <-> kv = 4g+(j&3)+16*(j>>2) == S^T C-layout position (m=j>>2, r=j&3)
    bf16x8 pfr[2];
#pragma unroll
    for (int n = 0; n < 2; ++n) {
      uint32_t dw[4];
#pragma unroll
      for (int m = 0; m < 2; ++m) {
        float p0 = fexp2(s2[m][n][0]) * bf2f(rdq[n][m][0]);
        float p1 = fexp2(s2[m][n][1]) * bf2f(rdq[n][m][1]);
        float p2 = fexp2(s2[m][n][2]) * bf2f(rdq[n][m][2]);
        float p3 = fexp2(s2[m][n][3]) * bf2f(rdq[n][m][3]);
        dw[m * 2 + 0] = cvtpk(p0, p1);
        dw[m * 2 + 1] = cvtpk(p2, p3);
      }
      union { uint32_t u[4]; bf16x8 v; } cv;
      cv.u[0] = dw[0]; cv.u[1] = dw[1]; cv.u[2] = dw[2]; cv.u[3] = dw[3];
      pfr[n] = cv.v;
    }

    // PV: ao^T[d64, q32] += V^T[d, kv32] * P^T[kv32, q32] (both in permuted k-order)
    __builtin_amdgcn_s_setprio(1);
#pragma unroll
    for (int dt = 0; dt < 4; ++dt) {
      const int vrow = dt * 16 + ln;
      bf16x8 vf = *(const bf16x8*)(Vs[buf] + vrow * 32 + ((g ^ (vrow & 3)) * 8));
#pragma unroll
      for (int n = 0; n < 2; ++n)
        ao[dt][n] = __builtin_amdgcn_mfma_f32_16x16x32_bf16(vf, pfr[n], ao[dt][n], 0, 0, 0);
    }
    __builtin_amdgcn_s_setprio(0);
    __syncthreads();  // tile t reads done before next-iter stage overwrites buf
  }

#pragma unroll
  for (int dt = 0; dt < 4; ++dt)
#pragma unroll
    for (int n = 0; n < 2; ++n) {
      u16x4 st;
#pragma unroll
      for (int r = 0; r < 4; ++r) st[r] = f2bf(ao[dt][n][r]);
      *(u16x4*)(Ab + (size_t)(b * SEQ + q0 + n * 16 + ln) * DMODEL + h * DKH + dt * 16 + g * 4) = st;
    }
}

extern "C" void kernel_launch(void* const* d_in, const int* in_sizes, int n_in,
                              void* d_out, int out_size, void* d_ws, size_t ws_size,
                              hipStream_t stream) {
  (void)in_sizes; (void)n_in; (void)out_size; (void)ws_size;
  const float* query = (const float*)d_in[0];
  const float* key   = (const float*)d_in[1];
  const float* value = (const float*)d_in[2];
  const float* Wq = (const float*)d_in[3];
  const float* bq = (const float*)d_in[4];
  const float* Wk = (const float*)d_in[5];
  const float* bk = (const float*)d_in[6];
  const float* Wv = (const float*)d_in[7];
  const float* bv = (const float*)d_in[8];
  const float* Wo = (const float*)d_in[9];
  const float* bo = (const float*)d_in[10];

  uint8_t* ws = (uint8_t*)d_ws;
  const size_t SZ = (size_t)4 * SEQ * DMODEL * 2;  // 16.78 MB per bf16 activation buffer
  const size_t WSZ = (size_t)DMODEL * DMODEL;      // 1M shorts per bf16 weight
  // ws layout: ws0=Qp (later Wob), ws1=Kp, ws2=Vt, ws3=weights (later Ab)
  unsigned short* Qp  = (unsigned short*)(ws);
  unsigned short* Wob = (unsigned short*)(ws);             // alias: after Qp consumed (post-flashk)
  unsigned short* Kp  = (unsigned short*)(ws + SZ);
  unsigned short* Vt  = (unsigned short*)(ws + 2 * SZ);
  unsigned short* Wqb = (unsigned short*)(ws + 3 * SZ);    // Wq|Wk|Wv bf16, contiguous
  unsigned short* Wkb = Wqb + WSZ;
  unsigned short* Wvb = Wqb + 2 * WSZ;
  unsigned short* Ab  = (unsigned short*)(ws + 3 * SZ);    // alias: after weights consumed
  unsigned short* rDb = (unsigned short*)d_out;

  cvtk<<<dim3(512, 3), 256, 0, stream>>>(Wq, Wk, Wv, Wqb, Wkb, Wvb);
  gemmqkv<<<1536, 256, 0, stream>>>(query, key, value, Wqb, bq, bk, bv, Qp, Kp, Vt);
  denomk<<<2048, 256, 0, stream>>>(Qp, Kp, rDb);
  flashk<<<2048, 128, 0, stream>>>(Qp, Kp, Vt, rDb, Ab);   // overwrites weights (dead)
  cvt1<<<512, 256, 0, stream>>>(Wo, Wob);                  // Qp dead -> park Wo bf16 in ws0
  gemmout<<<512, 256, 0, stream>>>(Ab, Wob, bo, (float*)d_out);  // overwrites rD
}

// Round 14
// 387.792 us; speedup vs baseline: 1.0432x; 1.0432x over previous
//
#include <hip/hip_runtime.h>
#include <stdint.h>

typedef __attribute__((ext_vector_type(8))) short bf16x8;
typedef __attribute__((ext_vector_type(4))) float f32x4;
typedef __attribute__((ext_vector_type(4))) float fl4;
typedef __attribute__((ext_vector_type(4))) unsigned short u16x4;
typedef __attribute__((ext_vector_type(8))) unsigned short u16x8;

constexpr int SEQ = 2048;
constexpr int DMODEL = 1024;
constexpr int NH = 16;
constexpr int DKH = 64;
constexpr float SEXP = 0.18033688f;  // log2(e)/8 — exp(s/8) == exp2(s*SEXP)

__device__ __forceinline__ unsigned short f2bf(float x) {
  union { float f; uint32_t u; } c;
  c.f = x;
  uint32_t u = c.u;
  u += 0x7FFFu + ((u >> 16) & 1u);
  return (unsigned short)(u >> 16);
}

__device__ __forceinline__ float bf2f(unsigned short u) {
  union { uint32_t u; float f; } c;
  c.u = ((uint32_t)u) << 16;
  return c.f;
}

__device__ __forceinline__ uint32_t cvtpk(float lo, float hi) {
  uint32_t r;
  asm("v_cvt_pk_bf16_f32 %0, %1, %2" : "=v"(r) : "v"(lo), "v"(hi));
  return r;
}

#if __has_builtin(__builtin_amdgcn_exp2f)
__device__ __forceinline__ float fexp2(float x) { return __builtin_amdgcn_exp2f(x); }
#else
__device__ __forceinline__ float fexp2(float x) { return exp2f(x); }
#endif

__device__ __forceinline__ int swz(int row) { return (row & 3) ^ ((row >> 2) & 3); }

__device__ __forceinline__ void gload16(const unsigned short* g, unsigned short* l) {
  __builtin_amdgcn_global_load_lds((const __attribute__((address_space(1))) void*)g,
                                   (__attribute__((address_space(3))) void*)l, 16, 0, 0);
}

// ---------------- fp32 -> bf16 conversions (weights only) ----------------
__global__ __launch_bounds__(256) void cvtk(
    const float* __restrict__ s0, const float* __restrict__ s1, const float* __restrict__ s2,
    unsigned short* __restrict__ d0, unsigned short* __restrict__ d1, unsigned short* __restrict__ d2) {
  const float* s = blockIdx.y == 0 ? s0 : blockIdx.y == 1 ? s1 : s2;
  unsigned short* d = blockIdx.y == 0 ? d0 : blockIdx.y == 1 ? d1 : d2;
  const size_t i = ((size_t)blockIdx.x * 256 + threadIdx.x) * 8;
  fl4 a = *(const fl4*)(s + i);
  fl4 c = *(const fl4*)(s + i + 4);
  u16x8 r;
#pragma unroll
  for (int j = 0; j < 4; ++j) { r[j] = f2bf(a[j]); r[4 + j] = f2bf(c[j]); }
  *(u16x8*)(d + i) = r;
}

__global__ __launch_bounds__(256) void cvt1(
    const float* __restrict__ s, unsigned short* __restrict__ d) {
  const size_t i = ((size_t)blockIdx.x * 256 + threadIdx.x) * 8;
  fl4 a = *(const fl4*)(s + i);
  fl4 c = *(const fl4*)(s + i + 4);
  u16x8 r;
#pragma unroll
  for (int j = 0; j < 4; ++j) { r[j] = f2bf(a[j]); r[4 + j] = f2bf(c[j]); }
  *(u16x8*)(d + i) = r;
}

// ---------------- Fused QKV projection: one launch, 1536 blocks (unchanged, proven) ----------------
__global__ __launch_bounds__(256, 2) void gemmqkv(
    const float* __restrict__ Xq, const float* __restrict__ Xk, const float* __restrict__ Xv,
    const unsigned short* __restrict__ Wb,   // [3][1024][1024] bf16, Wq|Wk|Wv
    const float* __restrict__ bq, const float* __restrict__ bk, const float* __restrict__ bv,
    unsigned short* __restrict__ Qp, unsigned short* __restrict__ Kp, unsigned short* __restrict__ Vt) {
  constexpr int K = DMODEL;
  __shared__ unsigned short As[2][128 * 32];
  __shared__ unsigned short Bs[2][128 * 32];
  const int tid = threadIdx.x;
  const int wave = tid >> 6, lane = tid & 63;
  const int g = lane >> 4, ln = lane & 15;
  const int o = blockIdx.x;                 // 1536 blocks
  const int x = o & 7, j = o >> 3;          // XCD x, j in [0,192)
  const int si = j >> 5, w = j & 31;        // 6 supertiles of 32 blocks per XCD
  const int seg = si >> 1;                  // 2 supertiles per segment per XCD
  const int r0 = (x * 8 + (si & 1) * 4 + (w & 3)) * 128;
  const int c0 = (w >> 2) * 128;
  const int wr = (wave >> 1) * 64, wc = (wave & 1) * 64;
  const int arow = tid >> 2, cc = tid & 3;

  const float* A = seg == 0 ? Xq : seg == 1 ? Xk : Xv;
  const unsigned short* Bw = Wb + (size_t)seg * DMODEL * DMODEL;
  const float* bias = seg == 0 ? bq : seg == 1 ? bk : bv;
  const float ascale = seg == 0 ? SEXP : 1.0f;

  f32x4 acc[4][4] = {};
  fl4 ar[2][2];

  auto LOADA = [&](int kt) {
#pragma unroll
    for (int i = 0; i < 2; ++i) {
      const size_t ao = (size_t)(r0 + arow + i * 64) * K + kt + cc * 8;
      ar[i][0] = *(const fl4*)(A + ao);
      ar[i][1] = *(const fl4*)(A + ao + 4);
    }
  };
  auto WRITEA = [&](int buf) {
#pragma unroll
    for (int i = 0; i < 2; ++i) {
      const int row = arow + i * 64;
      const int ch = (cc ^ swz(row)) * 8;
      union { uint32_t u[4]; u16x8 v; } pk;
      pk.u[0] = cvtpk(ar[i][0][0], ar[i][0][1]);
      pk.u[1] = cvtpk(ar[i][0][2], ar[i][0][3]);
      pk.u[2] = cvtpk(ar[i][1][0], ar[i][1][1]);
      pk.u[3] = cvtpk(ar[i][1][2], ar[i][1][3]);
      *(u16x8*)(As[buf] + row * 32 + ch) = pk.v;
    }
  };
  auto STAGEB = [&](int buf, int kt) {
#pragma unroll
    for (int i = 0; i < 2; ++i) {
      const int row = i * 64 + (tid >> 2);
      const int cs = ((tid & 3) ^ swz(row)) * 8;
      gload16(Bw + (size_t)(c0 + row) * K + kt + cs, Bs[buf] + (i * 256 + wave * 64) * 8);
    }
  };

  LOADA(0);
  WRITEA(0);
  STAGEB(0, 0);
  __syncthreads();

  for (int t = 0; t < K / 32; ++t) {
    const int buf = t & 1;
    if (t + 1 < K / 32) { LOADA((t + 1) * 32); STAGEB(buf ^ 1, (t + 1) * 32); }
    bf16x8 af[4], bfr[4];
#pragma unroll
    for (int m = 0; m < 4; ++m) {
      const int row = wr + m * 16 + ln;
      af[m] = *(const bf16x8*)(As[buf] + row * 32 + ((g ^ swz(row)) * 8));
    }
#pragma unroll
    for (int n = 0; n < 4; ++n) {
      const int row = wc + n * 16 + ln;
      bfr[n] = *(const bf16x8*)(Bs[buf] + row * 32 + ((g ^ swz(row)) * 8));
    }
#pragma unroll
    for (int m = 0; m < 4; ++m)
#pragma unroll
      for (int n = 0; n < 4; ++n)
        acc[m][n] = __builtin_amdgcn_mfma_f32_16x16x32_bf16(af[m], bfr[n], acc[m][n], 0, 0, 0);
    if (t + 1 < K / 32) WRITEA(buf ^ 1);  // buf^1 not read by anyone during iter t
    __syncthreads();
  }

  // epilogue: C/D layout col = lane&15, row = (lane>>4)*4 + reg
#pragma unroll
  for (int m = 0; m < 4; ++m) {
    const int row = r0 + wr + m * 16 + g * 4;
#pragma unroll
    for (int n = 0; n < 4; ++n) {
      const int col = c0 + wc + n * 16 + ln;
      const float bvv = bias[col];
      f32x4 v = acc[m][n];
      if (seg < 2) {
        unsigned short* C = seg == 0 ? Qp : Kp;
#pragma unroll
        for (int r = 0; r < 4; ++r) C[(size_t)(row + r) * DMODEL + col] = f2bf((v[r] + bvv) * ascale);
      } else {
        // V^T [b][h][d][s'], s' kv-permuted in each aligned 32-block:
        // s = 32*blk + 4*gp + rr + 16*mp -> s' = 32*blk + 8*gp + 4*mp + rr
        const int bb = row >> 11, sl = row & 2047;
        const int h = col >> 6, d = col & 63;
        const int sp = (sl & ~31) | (((sl >> 2) & 3) << 3) | (((sl >> 4) & 1) << 2);
        u16x4 pk;
#pragma unroll
        for (int r = 0; r < 4; ++r) pk[r] = f2bf(v[r] + bvv);
        *(u16x4*)(Vt + ((size_t)((bb * NH + h) * DKH + d)) * SEQ + sp) = pk;
      }
    }
  }
}

// ---------------- Output GEMM (unchanged, proven) ----------------
__global__ __launch_bounds__(256, 2) void gemmout(
    const unsigned short* __restrict__ A, const unsigned short* __restrict__ Bb,
    const float* __restrict__ bias, float* __restrict__ Cp) {
  constexpr int K = DMODEL;
  constexpr int N = DMODEL;
  __shared__ unsigned short As[2][128 * 32];
  __shared__ unsigned short Bs[2][128 * 32];
  const int tid = threadIdx.x;
  const int wave = tid >> 6, lane = tid & 63;
  const int g = lane >> 4, ln = lane & 15;
  const int o = blockIdx.x;                 // 512 blocks
  const int x = o & 7, idx = o >> 3;
  const int r0 = (x * 8 + (idx & 7)) * 128;
  const int c0 = (idx >> 3) * 128;
  const int wr = (wave >> 1) * 64, wc = (wave & 1) * 64;

  f32x4 acc[4][4] = {};

  auto STAGE = [&](int buf, int kt) {
#pragma unroll
    for (int i = 0; i < 2; ++i) {
      const int row = i * 64 + (tid >> 2);
      const int cs = ((tid & 3) ^ swz(row)) * 8;
      gload16(A + (size_t)(r0 + row) * K + kt + cs, As[buf] + (i * 256 + wave * 64) * 8);
      gload16(Bb + (size_t)(c0 + row) * K + kt + cs, Bs[buf] + (i * 256 + wave * 64) * 8);
    }
  };

  STAGE(0, 0);
  __syncthreads();

  for (int t = 0; t < K / 32; ++t) {
    const int buf = t & 1;
    if (t + 1 < K / 32) STAGE(buf ^ 1, (t + 1) * 32);
    bf16x8 af[4], bfr[4];
#pragma unroll
    for (int m = 0; m < 4; ++m) {
      const int row = wr + m * 16 + ln;
      af[m] = *(const bf16x8*)(As[buf] + row * 32 + ((g ^ swz(row)) * 8));
    }
#pragma unroll
    for (int n = 0; n < 4; ++n) {
      const int row = wc + n * 16 + ln;
      bfr[n] = *(const bf16x8*)(Bs[buf] + row * 32 + ((g ^ swz(row)) * 8));
    }
#pragma unroll
    for (int m = 0; m < 4; ++m)
#pragma unroll
      for (int n = 0; n < 4; ++n)
        acc[m][n] = __builtin_amdgcn_mfma_f32_16x16x32_bf16(af[m], bfr[n], acc[m][n], 0, 0, 0);
    __syncthreads();
  }

#pragma unroll
  for (int m = 0; m < 4; ++m) {
    const int row = r0 + wr + m * 16 + g * 4;
#pragma unroll
    for (int n = 0; n < 4; ++n) {
      const int col = c0 + wc + n * 16 + ln;
      const float bvv = bias[col];
      f32x4 v = acc[m][n];
#pragma unroll
      for (int r = 0; r < 4; ++r) Cp[(size_t)(row + r) * N + col] = v[r] + bvv;
    }
  }
}

// ---------------- Kernel A: head-softmax denominators (unchanged, proven) ----------------
__global__ __launch_bounds__(256, 3) void denomk(
    const unsigned short* __restrict__ Qp, const unsigned short* __restrict__ Kp,
    unsigned short* __restrict__ rDb) {
  __shared__ unsigned short Ks[2][128 * 64];
  const int tid = threadIdx.x, wave = tid >> 6, lane = tid & 63;
  const int g = lane >> 4, ln = lane & 15;
  const int o = blockIdx.x;
  const int l = (o & 7) * 256 + (o >> 3);
  const int b = l >> 9;
  const int qg = (l >> 4) & 31;
  const int kvg = l & 15;
  const int q0 = qg * 64, kvb = kvg * 128;
  const int kw = wave * 32;

  auto STAGE = [&](int buf, int h) {
#pragma unroll
    for (int i = 0; i < 4; ++i) {
      const int s = i * 256 + tid;
      const int row = s >> 3, c = s & 7;
      gload16(Kp + (size_t)(b * SEQ + kvb + row) * DMODEL + h * DKH + ((c ^ (row & 7)) * 8),
              Ks[buf] + (i * 256 + wave * 64) * 8);
    }
  };

  f32x4 psum[2][4] = {};

  STAGE(0, 0);
  __syncthreads();

  for (int h = 0; h < NH; ++h) {
    const int buf = h & 1;
    if (h + 1 < NH) STAGE(buf ^ 1, h + 1);
    bf16x8 qf[2][4];
#pragma unroll
    for (int ks = 0; ks < 2; ++ks)
#pragma unroll
      for (int n = 0; n < 4; ++n)
        qf[ks][n] = *(const bf16x8*)(Qp + (size_t)(b * SEQ + q0 + n * 16 + ln) * DMODEL + h * DKH + ks * 32 + g * 8);
    bf16x8 kf[2][2];
#pragma unroll
    for (int m = 0; m < 2; ++m)
#pragma unroll
      for (int ks = 0; ks < 2; ++ks) {
        const int r = kw + m * 16 + ln;
        const int cc = ks * 4 + g;
        kf[m][ks] = *(const bf16x8*)(Ks[buf] + r * 64 + ((cc ^ (r & 7)) * 8));
      }
    f32x4 s[2][4] = {};
#pragma unroll
    for (int m = 0; m < 2; ++m)
#pragma unroll
      for (int n = 0; n < 4; ++n) {
        s[m][n] = __builtin_amdgcn_mfma_f32_16x16x32_bf16(kf[m][0], qf[0][n], s[m][n], 0, 0, 0);
        s[m][n] = __builtin_amdgcn_mfma_f32_16x16x32_bf16(kf[m][1], qf[1][n], s[m][n], 0, 0, 0);
      }
#pragma unroll
    for (int m = 0; m < 2; ++m)
#pragma unroll
      for (int n = 0; n < 4; ++n)
#pragma unroll
        for (int r = 0; r < 4; ++r) psum[m][n][r] += fexp2(s[m][n][r]);  // Q pre-scaled by SEXP
    __syncthreads();
  }

#pragma unroll
  for (int m = 0; m < 2; ++m)
#pragma unroll
    for (int n = 0; n < 4; ++n) {
      u16x4 st;
#pragma unroll
      for (int r = 0; r < 4; ++r) st[r] = f2bf(1.0f / psum[m][n][r]);
      *(u16x4*)(rDb + (size_t)(b * SEQ + q0 + n * 16 + ln) * SEQ + kvb + kw + m * 16 + g * 4) = st;
    }
}

// ---------------- Kernel B: per-head flash PV — round-12 structure + rD register prefetch ----------------
// Block: (b, head h, q128); 4 waves each own q32; kv64 per barrier period (round-12, 159µs proven).
// NEW: rD ping-pong prefetch (rdA/rdB, statically unrolled) — the rdq loads are scattered
// (64 cache lines each, 4KB stride) and HBM-missing (per-XCD rD set 8.4MB > 4MB L2); loading
// substep u+1's rD during substep u's compute gives ~2k cy of latency cover vs ~900cy HBM.
// Values identical; no sync/LDS change. PV k-slot convention on BOTH operands (kv-permuted V).
__global__ __launch_bounds__(256, 4) void flashk(
    const unsigned short* __restrict__ Qp, const unsigned short* __restrict__ Kp,
    const unsigned short* __restrict__ Vt, const unsigned short* __restrict__ rDb,
    unsigned short* __restrict__ Ab) {
  __shared__ unsigned short Ks[2][64 * 64];   // [kv64][dk64], chunk-swizzled (8KB each)
  __shared__ unsigned short Vs[2][64 * 64];   // [d64][kv64-permuted], chunk-swizzled (8KB each)
  const int tid = threadIdx.x, wave = tid >> 6, lane = tid & 63;
  const int g = lane >> 4, ln = lane & 15;
  const int o = blockIdx.x;                  // 1024 blocks
  const int l = (o & 7) * 128 + (o >> 3);    // XCD chunk: 16 q-blocks sharing (b,h) K/V adjacent
  const int b = l >> 8;
  const int h = (l >> 4) & 15;
  const int q0 = (l & 15) * 128 + wave * 32;

  bf16x8 qf[2][2];
#pragma unroll
  for (int ks = 0; ks < 2; ++ks)
#pragma unroll
    for (int n = 0; n < 2; ++n)
      qf[ks][n] = *(const bf16x8*)(Qp + (size_t)(b * SEQ + q0 + n * 16 + ln) * DMODEL + h * DKH + ks * 32 + g * 8);

  f32x4 ao[4][2] = {};
  const size_t rbase0 = (size_t)(b * SEQ + q0 + ln) * SEQ;
  const size_t kbase = (size_t)(b * SEQ) * DMODEL + h * DKH;
  const size_t vbase = (size_t)((b * NH + h) * DKH) * SEQ;

  auto STAGE = [&](int buf, int kv0) {  // 4 gloads per thread (K 8KB + V 8KB)
#pragma unroll
    for (int i = 0; i < 2; ++i) {
      const int s = i * 256 + tid;
      const int row = s >> 3, c = s & 7;
      gload16(Kp + kbase + (size_t)(kv0 + row) * DMODEL + ((c ^ (row & 7)) * 8),
              Ks[buf] + (i * 256 + wave * 64) * 8);
    }
#pragma unroll
    for (int i = 0; i < 2; ++i) {
      const int s = i * 256 + tid;
      const int row = s >> 3, c = s & 7;
      gload16(Vt + vbase + (size_t)row * SEQ + kv0 + ((c ^ (row & 7)) * 8),
              Vs[buf] + (i * 256 + wave * 64) * 8);
    }
  };

  u16x4 rdA[2][2], rdB[2][2];
  auto LOADRD = [&](u16x4 (&dst)[2][2], int kv) {
#pragma unroll
    for (int n = 0; n < 2; ++n)
#pragma unroll
      for (int m = 0; m < 2; ++m)
        dst[n][m] = *(const u16x4*)(rDb + rbase0 + (size_t)(n * 16) * SEQ + kv + m * 16 + g * 4);
  };

  // One kv32 substep: prefetch next substep's rD into rdp, compute with rdu.
  auto SUBSTEP = [&](int buf, int si, int kv0, u16x4 (&rdu)[2][2], u16x4 (&rdp)[2][2], int kvnext) {
    LOADRD(rdp, kvnext);

    // QK^T: S^T[kv32, q32] (bit-identical MFMA sequence to denomk; Q pre-scaled by SEXP)
    f32x4 s2[2][2] = {};
    __builtin_amdgcn_s_setprio(1);
#pragma unroll
    for (int m = 0; m < 2; ++m) {
      const int row = si * 32 + m * 16 + ln;
#pragma unroll
      for (int ks = 0; ks < 2; ++ks) {
        const int cc = ks * 4 + g;
        bf16x8 kf = *(const bf16x8*)(Ks[buf] + row * 64 + ((cc ^ (row & 7)) * 8));
#pragma unroll
        for (int n = 0; n < 2; ++n)
          s2[m][n] = __builtin_amdgcn_mfma_f32_16x16x32_bf16(kf, qf[ks][n], s2[m][n], 0, 0, 0);
      }
    }
    __builtin_amdgcn_s_setprio(0);

    // P = exp2(S') * rD, packed in-register straight into the permuted B-frag:
    // elem j of lane-group g <-> kv = 4g+(j&3)+16*(j>>2) == S^T C-layout position (m=j>>2, r=j&3)
    bf16x8 pfr[2];
#pragma unroll
    for (int n = 0; n < 2; ++n) {
      uint32_t dw[4];
#pragma unroll
      for (int m = 0; m < 2; ++m) {
        float p0 = fexp2(s2[m][n][0]) * bf2f(rdu[n][m][0]);
        float p1 = fexp2(s2[m][n][1]) * bf2f(rdu[n][m][1]);
        float p2 = fexp2(s2[m][n][2]) * bf2f(rdu[n][m][2]);
        float p3 = fexp2(s2[m][n][3]) * bf2f(rdu[n][m][3]);
        dw[m * 2 + 0] = cvtpk(p0, p1);
        dw[m * 2 + 1] = cvtpk(p2, p3);
      }
      union { uint32_t u[4]; bf16x8 v; } cv;
      cv.u[0] = dw[0]; cv.u[1] = dw[1]; cv.u[2] = dw[2]; cv.u[3] = dw[3];
      pfr[n] = cv.v;
    }

    // PV: ao^T[d64, q32] += V^T[d, kv32] * P^T[kv32, q32] (both in permuted k-order)
    __builtin_amdgcn_s_setprio(1);
#pragma unroll
    for (int dt = 0; dt < 4; ++dt) {
      const int vrow = dt * 16 + ln;
      const int vc = si * 4 + g;
      bf16x8 vf = *(const bf16x8*)(Vs[buf] + vrow * 64 + ((vc ^ (vrow & 7)) * 8));
#pragma unroll
      for (int n = 0; n < 2; ++n)
        ao[dt][n] = __builtin_amdgcn_mfma_f32_16x16x32_bf16(vf, pfr[n], ao[dt][n], 0, 0, 0);
    }
    __builtin_amdgcn_s_setprio(0);
  };

  LOADRD(rdA, 0);   // rD for substep u=0
  STAGE(0, 0);
  __syncthreads();

  for (int t = 0; t < SEQ / 64; ++t) {
    const int kv0 = t * 64, buf = t & 1;
    if (t + 1 < SEQ / 64) STAGE(buf ^ 1, kv0 + 64);
    SUBSTEP(buf, 0, kv0, rdA, rdB, kv0 + 32);                  // use rdA, prefetch rdB
    SUBSTEP(buf, 1, kv0, rdB, rdA, (kv0 + 64) & (SEQ - 1));    // use rdB, prefetch rdA (tail wraps; dead)
    __syncthreads();  // tile t reads done before next-iter stage overwrites buf
  }

#pragma unroll
  for (int dt = 0; dt < 4; ++dt)
#pragma unroll
    for (int n = 0; n < 2; ++n) {
      u16x4 st;
#pragma unroll
      for (int r = 0; r < 4; ++r) st[r] = f2bf(ao[dt][n][r]);
      *(u16x4*)(Ab + (size_t)(b * SEQ + q0 + n * 16 + ln) * DMODEL + h * DKH + dt * 16 + g * 4) = st;
    }
}

extern "C" void kernel_launch(void* const* d_in, const int* in_sizes, int n_in,
                              void* d_out, int out_size, void* d_ws, size_t ws_size,
                              hipStream_t stream) {
  (void)in_sizes; (void)n_in; (void)out_size; (void)ws_size;
  const float* query = (const float*)d_in[0];
  const float* key   = (const float*)d_in[1];
  const float* value = (const float*)d_in[2];
  const float* Wq = (const float*)d_in[3];
  const float* bq = (const float*)d_in[4];
  const float* Wk = (const float*)d_in[5];
  const float* bk = (const float*)d_in[6];
  const float* Wv = (const float*)d_in[7];
  const float* bv = (const float*)d_in[8];
  const float* Wo = (const float*)d_in[9];
  const float* bo = (const float*)d_in[10];

  uint8_t* ws = (uint8_t*)d_ws;
  const size_t SZ = (size_t)4 * SEQ * DMODEL * 2;  // 16.78 MB per bf16 activation buffer
  const size_t WSZ = (size_t)DMODEL * DMODEL;      // 1M shorts per bf16 weight
  // ws layout: ws0=Qp (later Wob), ws1=Kp, ws2=Vt, ws3=weights (later Ab)
  unsigned short* Qp  = (unsigned short*)(ws);
  unsigned short* Wob = (unsigned short*)(ws);             // alias: after Qp consumed (post-flashk)
  unsigned short* Kp  = (unsigned short*)(ws + SZ);
  unsigned short* Vt  = (unsigned short*)(ws + 2 * SZ);
  unsigned short* Wqb = (unsigned short*)(ws + 3 * SZ);    // Wq|Wk|Wv bf16, contiguous
  unsigned short* Wkb = Wqb + WSZ;
  unsigned short* Wvb = Wqb + 2 * WSZ;
  unsigned short* Ab  = (unsigned short*)(ws + 3 * SZ);    // alias: after weights consumed
  unsigned short* rDb = (unsigned short*)d_out;

  cvtk<<<dim3(512, 3), 256, 0, stream>>>(Wq, Wk, Wv, Wqb, Wkb, Wvb);
  gemmqkv<<<1536, 256, 0, stream>>>(query, key, value, Wqb, bq, bk, bv, Qp, Kp, Vt);
  denomk<<<2048, 256, 0, stream>>>(Qp, Kp, rDb);
  flashk<<<1024, 256, 0, stream>>>(Qp, Kp, Vt, rDb, Ab);   // overwrites weights (dead)
  cvt1<<<512, 256, 0, stream>>>(Wo, Wob);                  // Qp dead -> park Wo bf16 in ws0
  gemmout<<<512, 256, 0, stream>>>(Ab, Wob, bo, (float*)d_out);  // overwrites rD
}